// Round 6
// baseline (131.745 us; speedup 1.0000x reference)
//
#include <hip/hip_runtime.h>

// Orbitals_ent: sorted-occupancy gather.
// x: (2048, 256) int32 in {-1,+1}
// orbitals_mf: (512, 256) f32, orbitals_hf: (512, 64) f32
// out: (2048, 256, 320) f32 = orbitals_full[idx], idx = ascending indices of
// occupied spin-orbitals (ups first, then downs, each ascending by site).
//
// R1: row-gather from L2, 132 us (5.1 TB/s write; fill-kernel ceiling 6.7).
// R2: nontemporal stores + unroll: neutral (134 us).
// R3: LDS column slices — FAILED (hf output offset bug).
// R4: R3 fixed: 139 us -> read-interference theory dead.
// R5: reg-batched loads + address-ordered stores: 128 us (small win).
// R6: narrow the WRITE FRONT: 512 blocks x 1024 threads, 4 consecutive
//     batches per block processed sequentially (block streams 1.28 MB in
//     order). 512 concurrent write streams instead of 2048 -> DRAM page
//     locality like the fill kernel's moving front.

#define NBATCH 2048
#define NS 256   // sites (= rows gathered per batch)
#define NMF 256  // mf columns
#define NHF 64   // hf columns
#define NROW 320 // NMF + NHF
#define BPB 4    // batches per block
#define THREADS 1024

typedef float v4f __attribute__((ext_vector_type(4)));

__global__ __launch_bounds__(THREADS) void gather_orbitals(
    const int* __restrict__ x,
    const float* __restrict__ mf,
    const float* __restrict__ hf,
    float* __restrict__ out)
{
    __shared__ int srcs[BPB * NS];  // per-batch dest row -> source row
    __shared__ int wtot[16];        // per-wave up counts

    const int bstart = blockIdx.x * BPB;
    const int tid  = threadIdx.x;
    const int q    = tid >> 8;        // batch-local index 0..3 (prologue)
    const int t    = tid & 255;       // site index within batch
    const int gw   = tid >> 6;        // global wave 0..15
    const int wl   = gw & 3;          // wave within batch
    const int lane = tid & 63;

    // --- prologue: build all 4 permutations at once ---
    const int xv = x[(size_t)(bstart + q) * NS + t];
    const bool up = (xv == 1);
    const unsigned long long m = __ballot(up);            // 64-bit on CDNA
    const int lane_ex = __popcll(m & ((1ull << lane) - 1ull));
    if (lane == 0) wtot[gw] = __popcll(m);
    __syncthreads();

    int woff = 0, nup = 0;
#pragma unroll
    for (int w = 0; w < 4; ++w) {
        const int c = wtot[q * 4 + w];
        if (w < wl) woff += c;
        nup += c;
    }
    const int upex = woff + lane_ex;        // #ups among this batch's sites < t
    const int dest = up ? upex : (nup + (t - upex));
    srcs[q * NS + dest] = up ? t : (NS + t);
    __syncthreads();

    const int j16 = lane >> 4;   // which of 4 rows this lane's hf chunk feeds
    const int l16 = lane & 15;   // float4 index within a 64-float hf tail

    // --- store phase: batches sequentially, 16 waves x 16 rows per batch ---
#pragma unroll 1
    for (int qq = 0; qq < BPB; ++qq) {
        const int* srcq = srcs + qq * NS;
        float* outq = out + (size_t)(bstart + qq) * NS * NROW;

#pragma unroll 2
        for (int c = 0; c < 4; ++c) {
            const int rbase = gw * 16 + c * 4;

            int s[4];
#pragma unroll
            for (int k = 0; k < 4; ++k) s[k] = srcq[rbase + k];
            const int sh = srcq[rbase + j16];

            v4f vm[4];
#pragma unroll
            for (int k = 0; k < 4; ++k)
                vm[k] = ((const v4f*)(mf + (size_t)s[k] * NMF))[lane];
            const v4f vh = ((const v4f*)(hf + (size_t)sh * NHF))[l16];

            // strict ascending address order within the 4-row chunk
#pragma unroll
            for (int k = 0; k < 4; ++k)
                ((v4f*)(outq + (size_t)(rbase + k) * NROW))[lane] = vm[k];
            ((v4f*)(outq + (size_t)(rbase + j16) * NROW + NMF))[l16] = vh;
        }
    }
}

extern "C" void kernel_launch(void* const* d_in, const int* in_sizes, int n_in,
                              void* d_out, int out_size, void* d_ws, size_t ws_size,
                              hipStream_t stream) {
    const int*   x  = (const int*)d_in[0];
    const float* mf = (const float*)d_in[1];
    const float* hf = (const float*)d_in[2];
    float* out = (float*)d_out;

    gather_orbitals<<<dim3(NBATCH / BPB), dim3(THREADS), 0, stream>>>(x, mf, hf, out);
}